// Round 7
// baseline (259.920 us; speedup 1.0000x reference)
//
#include <hip/hip_runtime.h>
#include <hip/hip_bf16.h>

#define B_ 4
#define C_ 256
#define CI_ 128
#define P_ 4096
#define LOG2E 1.44269504088896340736f

typedef __attribute__((ext_vector_type(8))) _Float16 half8;
typedef __attribute__((ext_vector_type(2))) __fp16 fp16x2;
typedef __attribute__((ext_vector_type(8))) short short8;
typedef __attribute__((ext_vector_type(4))) short short4v;
typedef __attribute__((ext_vector_type(4))) float floatx4;
typedef __attribute__((ext_vector_type(16))) float floatx16;

__device__ __forceinline__ float bf2f(ushort h) {
  union { unsigned u; float f; } v; v.u = ((unsigned)h) << 16; return v.f;
}
__device__ __forceinline__ ushort f2bf(float f) {
  union { float f; unsigned u; } v; v.f = f;
  unsigned r = v.u + 0x7FFFu + ((v.u >> 16) & 1u);
  return (ushort)(r >> 16);
}
__device__ __forceinline__ ushort f2h(float f) {
  _Float16 h = (_Float16)f;
  union { _Float16 h; ushort u; } v; v.h = h; return v.u;
}
__device__ __forceinline__ uint pk2h(float a, float b) {
  union { fp16x2 h2; uint u; } cv;
  cv.h2 = __builtin_amdgcn_cvt_pkrtz(a, b);
  return cv.u;
}

#define MFMA16(a, b, c) __builtin_amdgcn_mfma_f32_16x16x32_f16((a), (b), (c), 0, 0, 0)
#define MFMA32(a, b, c) __builtin_amdgcn_mfma_f32_32x32x16_f16((a), (b), (c), 0, 0, 0)

// Per-block dtype probe (deterministic). bf16 N(0,1) even-ushort exponents in
// [0x70,0x84] ~100%; fp32 low-mantissa halves ~8%. Call from all 256 threads.
__device__ __forceinline__ int detect_bf16(const ushort* __restrict__ xu) {
  __shared__ int cnt_;
  if (threadIdx.x == 0) cnt_ = 0;
  __syncthreads();
  int local = 0;
  int t = threadIdx.x & 255;
#pragma unroll
  for (int s = 0; s < 8; ++s) {
    ushort u = xu[(t * 8 + s) * 2];
    int e = (u >> 7) & 0xFF;
    local += (e >= 0x70 && e <= 0x84) ? 1 : 0;
  }
  atomicAdd(&cnt_, local);
  __syncthreads();
  return cnt_ > 1024;
}

// Merged: x transpose (blocks 0..1023), weight cvt (1024..1535), bias cvt.
__global__ void k_trc(const void* __restrict__ xv, ushort* __restrict__ xT,
                      const void* __restrict__ s0, const void* __restrict__ s1,
                      const void* __restrict__ s2, const void* __restrict__ s3,
                      const void* __restrict__ tbv, const void* __restrict__ pbv,
                      const void* __restrict__ gbv, const void* __restrict__ wbv,
                      ushort* __restrict__ dstW, float* __restrict__ biasf) {
  int is_bf16 = detect_bf16((const ushort*)xv);
  int bid = blockIdx.x;
  int t = threadIdx.x;
  if (bid < 1024) {
    __shared__ __align__(16) ushort tile[64][72];
    int pb = (bid & 63) * 64;
    int cb = ((bid >> 6) & 3) * 64;
    int b = bid >> 8;
#pragma unroll
    for (int it = 0; it < 2; ++it) {
      int lin = it * 256 + t;
      int c = lin >> 3;
      int p = (lin & 7) * 8;
      size_t base = ((size_t)(b * C_) + cb + c) * P_ + pb + p;
      float vv[8];
      if (is_bf16) {
        short8 v = *(const short8*)((const ushort*)xv + base);
#pragma unroll
        for (int i = 0; i < 8; ++i) vv[i] = bf2f((ushort)v[i]);
      } else {
        const float* xf = (const float*)xv;
        float4 v0 = *(const float4*)(xf + base);
        float4 v1 = *(const float4*)(xf + base + 4);
        vv[0] = v0.x; vv[1] = v0.y; vv[2] = v0.z; vv[3] = v0.w;
        vv[4] = v1.x; vv[5] = v1.y; vv[6] = v1.z; vv[7] = v1.w;
      }
#pragma unroll
      for (int i = 0; i < 8; ++i) {
        int iw = (i + t) & 7;
        tile[p + iw][c] = f2h(vv[iw]);
      }
    }
    __syncthreads();
#pragma unroll
    for (int it = 0; it < 2; ++it) {
      int lin = it * 256 + t;
      int p = lin >> 3;
      int c = (lin & 7) * 8;
      short8 v = *(const short8*)&tile[p][c];
      *(short8*)(xT + ((size_t)(b * P_) + pb + p) * C_ + cb + c) = v;
    }
  } else if (bid < 1536) {
    int wid = bid - 1024;
    int a = wid >> 7;
    const void* srcs[4] = {s0, s1, s2, s3};
    int i = (wid & 127) * 256 + t;
    float v = is_bf16 ? bf2f(((const ushort*)srcs[a])[i]) : ((const float*)srcs[a])[i];
    dstW[a * 32768 + i] = f2h(v);
  } else {
    int idx = (bid - 1536) * 256 + t;
    if (idx < 640) {
      const void* src; int loc;
      if (idx < 128)      { src = tbv; loc = idx; }
      else if (idx < 256) { src = pbv; loc = idx - 128; }
      else if (idx < 384) { src = gbv; loc = idx - 256; }
      else                { src = wbv; loc = idx - 384; }
      float v = is_bf16 ? bf2f(((const ushort*)src)[loc]) : ((const float*)src)[loc];
      biasf[idx] = v;
    }
  }
}

// Projections: thetaT/phiT (B,P,CI) f16 (p-major), g (B,CI,P) f16, + bias.
__global__ __launch_bounds__(256, 4) void k_proj(
    const ushort* __restrict__ xT, const ushort* __restrict__ Wh,
    const float* __restrict__ biasf,
    ushort* __restrict__ thetaT, ushort* __restrict__ phiT,
    ushort* __restrict__ g) {
  int t = threadIdx.x;
  int w = t >> 6, lane = t & 63, l = lane & 15, q = lane >> 4;
  int pblk = blockIdx.x * 32;
  int b = blockIdx.y;
  floatx4 acc[2][6];
#pragma unroll
  for (int ps = 0; ps < 2; ++ps)
#pragma unroll
    for (int ks = 0; ks < 6; ++ks) acc[ps][ks] = (floatx4){0.f, 0.f, 0.f, 0.f};
  const ushort* xrow[2];
#pragma unroll
  for (int ps = 0; ps < 2; ++ps)
    xrow[ps] = xT + ((size_t)(b * P_) + pblk + ps * 16 + l) * C_;
  const ushort* wrow[6];
  int prj[6], kloc[6];
#pragma unroll
  for (int ks = 0; ks < 6; ++ks) {
    int kg = w * 96 + ks * 16;
    prj[ks] = kg >> 7;
    kloc[ks] = kg & 127;
    wrow[ks] = Wh + prj[ks] * 32768 + (size_t)(kloc[ks] + l) * C_;
  }
  for (int c = 0; c < C_; c += 32) {
    half8 av[2], wv[6];
#pragma unroll
    for (int ps = 0; ps < 2; ++ps) av[ps] = *(const half8*)(xrow[ps] + c + q * 8);
#pragma unroll
    for (int ks = 0; ks < 6; ++ks) wv[ks] = *(const half8*)(wrow[ks] + c + q * 8);
#pragma unroll
    for (int ps = 0; ps < 2; ++ps)
#pragma unroll
      for (int ks = 0; ks < 6; ++ks)
        acc[ps][ks] = MFMA16(av[ps], wv[ks], acc[ps][ks]);
  }
#pragma unroll
  for (int ks = 0; ks < 6; ++ks) {
    float bias = biasf[prj[ks] * 128 + kloc[ks] + l];
#pragma unroll
    for (int ps = 0; ps < 2; ++ps) {
      floatx4 d = acc[ps][ks];
      if (prj[ks] < 2) {
        ushort* dst = (prj[ks] == 0 ? thetaT : phiT) +
                      ((size_t)(b * P_) + pblk + ps * 16 + q * 4) * CI_ + kloc[ks] + l;
#pragma unroll
        for (int r = 0; r < 4; ++r) dst[(size_t)r * CI_] = f2h(d[r] + bias);
      } else {
        ushort* dst = g + ((size_t)(b * CI_) + kloc[ks] + l) * P_ + pblk + ps * 16 + q * 4;
        short4v pk;
#pragma unroll
        for (int r = 0; r < 4; ++r) pk[r] = (short)f2h(d[r] + bias);
        *(short4v*)dst = pk;
      }
    }
  }
}

// Pass A: partial sums of exp2(S*log2e - 64) over j-splits.
__global__ __launch_bounds__(256, 2) void k_stats(
    const ushort* __restrict__ phiT, const ushort* __restrict__ thetaT,
    float* __restrict__ part) {
  int t = threadIdx.x, w = t >> 6, lane = t & 63, l = lane & 15, q = lane >> 4;
  int i0 = blockIdx.x * 256, j0 = blockIdx.y * 512, b = blockIdx.z;
  half8 av[4][4];
#pragma unroll
  for (int is = 0; is < 4; ++is) {
    const ushort* pr = phiT + ((size_t)(b * P_) + i0 + w * 64 + is * 16 + l) * CI_;
#pragma unroll
    for (int ks = 0; ks < 4; ++ks) av[is][ks] = *(const half8*)(pr + ks * 32 + q * 8);
  }
  float sum[4][4];
#pragma unroll
  for (int is = 0; is < 4; ++is)
#pragma unroll
    for (int r = 0; r < 4; ++r) sum[is][r] = 0.f;
  const ushort* tb0 = thetaT + (size_t)b * P_ * CI_;
  for (int jc = 0; jc < 16; ++jc) {
    int j = j0 + jc * 32;
    half8 bv[2][4];
#pragma unroll
    for (int js = 0; js < 2; ++js) {
      const ushort* tr = tb0 + (size_t)(j + js * 16 + l) * CI_;
#pragma unroll
      for (int ks = 0; ks < 4; ++ks) bv[js][ks] = *(const half8*)(tr + ks * 32 + q * 8);
    }
    floatx4 accS[4][2];
#pragma unroll
    for (int is = 0; is < 4; ++is)
#pragma unroll
      for (int js = 0; js < 2; ++js) accS[is][js] = (floatx4){0.f, 0.f, 0.f, 0.f};
#pragma unroll
    for (int ks = 0; ks < 4; ++ks)
#pragma unroll
      for (int is = 0; is < 4; ++is)
#pragma unroll
        for (int js = 0; js < 2; ++js)
          accS[is][js] = MFMA16(av[is][ks], bv[js][ks], accS[is][js]);
#pragma unroll
    for (int is = 0; is < 4; ++is)
#pragma unroll
      for (int js = 0; js < 2; ++js)
#pragma unroll
        for (int r = 0; r < 4; ++r)
          sum[is][r] += exp2f(fmaf(accS[is][js][r], LOG2E, -64.f));
  }
#pragma unroll
  for (int d = 1; d < 16; d <<= 1)
#pragma unroll
    for (int is = 0; is < 4; ++is)
#pragma unroll
      for (int r = 0; r < 4; ++r) sum[is][r] += __shfl_xor(sum[is][r], d, 64);
  if (l == 0) {
#pragma unroll
    for (int is = 0; is < 4; ++is)
#pragma unroll
      for (int r = 0; r < 4; ++r)
        part[((size_t)blockIdx.y * B_ + b) * P_ + i0 + w * 64 + is * 16 + q * 4 + r] =
            sum[is][r];
  }
}

// Combine 8 partials -> o2 = log2(sumexp) + 64
__global__ void k_lse(const float* __restrict__ part, float* __restrict__ o2) {
  int idx = blockIdx.x * 256 + threadIdx.x;  // < B_*P_
  float s = 0.f;
#pragma unroll
  for (int p = 0; p < 8; ++p) s += part[(size_t)p * (B_ * P_) + idx];
  o2[idx] = log2f(s) + 64.f;
}

// Pass B v3: 32x32x16 MFMA, E kept in registers (xor-32 shuffle transform),
// NO per-chunk barriers, NO eL. Block: j-tile 64, i-half 2048, all 128 c.
// Wave w owns i-blocks (u*4+w)*32; accA = att[128c x 64j] partial over its i.
// End: waves 1-3 dump f16 partials to LDS, wave 0 reduces + stores.
// A-frag (32x32x16): A[m=lane&31][k=(lane>>5)*8+e]; B same; D: col=lane&31,
// row=(reg&3)+8*(reg>>2)+4*(lane>>5).
__global__ __launch_bounds__(256, 2) void k_attn(
    const ushort* __restrict__ phiT, const ushort* __restrict__ thetaT,
    const ushort* __restrict__ g, const float* __restrict__ o2,
    ushort* __restrict__ attP0, ushort* __restrict__ attP1) {
  __shared__ __align__(16) ushort thL[64 * 136];
  __shared__ __align__(16) uint redbuf[3 * 4096];
  int t = threadIdx.x;
  int w = t >> 6, lane = t & 63;
  int m = lane & 31, h = lane >> 5;
  int j0 = blockIdx.x * 64, ih = blockIdx.y, b = blockIdx.z;
  // stage theta[64j][128k] -> thL (row stride 136 halves)
#pragma unroll
  for (int it = 0; it < 4; ++it) {
    int lin = it * 256 + t;
    int row = lin >> 4;
    int col = (lin & 15) * 8;
    *(short8*)&thL[row * 136 + col] =
        *(const short8*)(thetaT + ((size_t)(b * P_) + j0 + row) * CI_ + col);
  }
  floatx16 accA[4][2];
  floatx16 zz = {0.f,0.f,0.f,0.f,0.f,0.f,0.f,0.f,0.f,0.f,0.f,0.f,0.f,0.f,0.f,0.f};
#pragma unroll
  for (int cs = 0; cs < 4; ++cs)
#pragma unroll
    for (int js = 0; js < 2; ++js) accA[cs][js] = zz;
  __syncthreads();
  int istart = ih * 2048;
  const float* orow = o2 + b * P_;
  for (int u = 0; u < 16; ++u) {
    int ib = istart + (u * 4 + w) * 32;
    // phi A-frags (8 k-tiles)
    half8 aph[8];
    const ushort* pr = phiT + ((size_t)(b * P_) + ib + m) * CI_ + h * 8;
#pragma unroll
    for (int kt = 0; kt < 8; ++kt) aph[kt] = *(const half8*)(pr + kt * 16);
    // o2 for this lane's 16 C-rows: i = ib + (rg&3) + 8*(rg>>2) + 4h
    float ovs[16];
    {
      float4 o0 = *(const float4*)(orow + ib + 4 * h);
      float4 o1 = *(const float4*)(orow + ib + 8 + 4 * h);
      float4 o2v = *(const float4*)(orow + ib + 16 + 4 * h);
      float4 o3 = *(const float4*)(orow + ib + 24 + 4 * h);
      ovs[0]=o0.x; ovs[1]=o0.y; ovs[2]=o0.z; ovs[3]=o0.w;
      ovs[4]=o1.x; ovs[5]=o1.y; ovs[6]=o1.z; ovs[7]=o1.w;
      ovs[8]=o2v.x; ovs[9]=o2v.y; ovs[10]=o2v.z; ovs[11]=o2v.w;
      ovs[12]=o3.x; ovs[13]=o3.y; ovs[14]=o3.z; ovs[15]=o3.w;
    }
    // phase 1: S[32i x 64j]
    floatx16 accS[2];
    accS[0] = zz; accS[1] = zz;
#pragma unroll
    for (int kt = 0; kt < 8; ++kt)
#pragma unroll
      for (int js = 0; js < 2; ++js) {
        half8 bf = *(const half8*)&thL[(js * 32 + m) * 136 + kt * 16 + h * 8];
        accS[js] = MFMA32(aph[kt], bf, accS[js]);
      }
    // E = exp2(S*log2e - o), converted C-layout -> B-frag layout in registers
    half8 efr[2][2];
#pragma unroll
    for (int js = 0; js < 2; ++js) {
      float e[16];
#pragma unroll
      for (int rg = 0; rg < 16; ++rg)
        e[rg] = exp2f(fminf(fmaf(accS[js][rg], LOG2E, -ovs[rg]), 8.f));
      uint pk[8], qq[8];
#pragma unroll
      for (int p2 = 0; p2 < 8; ++p2) pk[p2] = pk2h(e[p2 * 2], e[p2 * 2 + 1]);
#pragma unroll
      for (int p2 = 0; p2 < 8; ++p2) qq[p2] = (uint)__shfl_xor((int)pk[p2], 32, 64);
      union { uint u[4]; half8 v; } f0, f1;
      f0.u[0] = h ? qq[2] : pk[0];
      f0.u[1] = h ? qq[3] : pk[1];
      f0.u[2] = h ? pk[2] : qq[0];
      f0.u[3] = h ? pk[3] : qq[1];
      f1.u[0] = h ? qq[6] : pk[4];
      f1.u[1] = h ? qq[7] : pk[5];
      f1.u[2] = h ? pk[6] : qq[4];
      f1.u[3] = h ? pk[7] : qq[5];
      efr[js][0] = f0.v;
      efr[js][1] = f1.v;
    }
    // phase 2: attA[c][j] += g[c][i] * E[i][j]
#pragma unroll
    for (int kf = 0; kf < 2; ++kf) {
      const ushort* grb = g + (size_t)(b * CI_) * P_ + ib + kf * 16 + h * 8;
#pragma unroll
      for (int cs = 0; cs < 4; ++cs) {
        half8 ag = *(const half8*)(grb + (size_t)(cs * 32 + m) * P_);
#pragma unroll
        for (int js = 0; js < 2; ++js)
          accA[cs][js] = MFMA32(ag, efr[js][kf], accA[cs][js]);
      }
    }
  }
  // cross-wave reduction: waves 1-3 write f16-packed partials, wave 0 sums.
  if (w > 0) {
    uint* dst = &redbuf[(w - 1) * 4096];
#pragma unroll
    for (int cs = 0; cs < 4; ++cs)
#pragma unroll
      for (int js = 0; js < 2; ++js)
#pragma unroll
        for (int p2 = 0; p2 < 8; ++p2)
          dst[(cs * 16 + js * 8 + p2) * 64 + lane] =
              pk2h(accA[cs][js][p2 * 2], accA[cs][js][p2 * 2 + 1]);
  }
  __syncthreads();
  if (w == 0) {
    ushort* ap = (ih == 0 ? attP0 : attP1);
#pragma unroll
    for (int cs = 0; cs < 4; ++cs)
#pragma unroll
      for (int js = 0; js < 2; ++js)
#pragma unroll
        for (int p2 = 0; p2 < 8; ++p2) {
          float s0 = accA[cs][js][p2 * 2], s1 = accA[cs][js][p2 * 2 + 1];
          int d = (cs * 16 + js * 8 + p2) * 64 + lane;
#pragma unroll
          for (int ww = 0; ww < 3; ++ww) {
            union { uint u; fp16x2 h2; } cv;
            cv.u = redbuf[ww * 4096 + d];
            s0 += (float)cv.h2[0];
            s1 += (float)cv.h2[1];
          }
          int rg = p2 * 2;
          int c = cs * 32 + (rg & 3) + 8 * (rg >> 2) + 4 * h;
          int j = j0 + js * 32 + m;
          *(uint*)(ap + ((size_t)(b * P_) + j) * CI_ + c) = pk2h(s0, s1);
        }
  }
}

// Final: attsum = attP0+attP1 (f16, [p][c]); out = Ww*attsum + wb + x.
__global__ __launch_bounds__(256, 4) void k_out(
    const ushort* __restrict__ attP0, const ushort* __restrict__ attP1,
    const ushort* __restrict__ wwh, const float* __restrict__ biasf,
    const void* __restrict__ xv, void* __restrict__ outv) {
  int is_bf16 = detect_bf16((const ushort*)xv);
  int t = threadIdx.x;
  int w = t >> 6, lane = t & 63, l = lane & 15, q = lane >> 4;
  int p0 = blockIdx.x * 32, b = blockIdx.y;
  floatx4 accR[4][2];
#pragma unroll
  for (int kk = 0; kk < 4; ++kk)
#pragma unroll
    for (int js = 0; js < 2; ++js) accR[kk][js] = (floatx4){0.f, 0.f, 0.f, 0.f};
#pragma unroll
  for (int ks = 0; ks < 4; ++ks) {
    half8 wf[4], af[2];
#pragma unroll
    for (int kk = 0; kk < 4; ++kk)
      wf[kk] = *(const half8*)(wwh + (size_t)(w * 64 + kk * 16 + l) * CI_ + ks * 32 + q * 8);
#pragma unroll
    for (int js = 0; js < 2; ++js) {
      size_t off = ((size_t)(b * P_) + p0 + js * 16 + l) * CI_ + ks * 32 + q * 8;
      half8 s = *(const half8*)(attP0 + off);
      s = s + *(const half8*)(attP1 + off);
      af[js] = s;
    }
#pragma unroll
    for (int kk = 0; kk < 4; ++kk)
#pragma unroll
      for (int js = 0; js < 2; ++js) accR[kk][js] = MFMA16(wf[kk], af[js], accR[kk][js]);
  }
#pragma unroll
  for (int kk = 0; kk < 4; ++kk)
#pragma unroll
    for (int r = 0; r < 4; ++r) {
      int c = w * 64 + kk * 16 + q * 4 + r;
      float bias = biasf[384 + c];
#pragma unroll
      for (int js = 0; js < 2; ++js) {
        int p = p0 + js * 16 + l;
        size_t idx = ((size_t)(b * C_) + c) * P_ + p;
        float val = accR[kk][js][r] + bias;
        if (is_bf16) {
          ((ushort*)outv)[idx] = f2bf(bf2f(((const ushort*)xv)[idx]) + val);
        } else {
          ((float*)outv)[idx] = ((const float*)xv)[idx] + val;
        }
      }
    }
}

extern "C" void kernel_launch(void* const* d_in, const int* in_sizes, int n_in,
                              void* d_out, int out_size, void* d_ws, size_t ws_size,
                              hipStream_t stream) {
  const void* x  = d_in[0];
  const void* tw = d_in[1];
  const void* tb = d_in[2];
  const void* pw = d_in[3];
  const void* pb = d_in[4];
  const void* gw = d_in[5];
  const void* gb = d_in[6];
  const void* ww = d_in[7];
  const void* wb = d_in[8];
  char* ws = (char*)d_ws;
  // meta region [0, 1 MB)
  float*  o2     = (float*)(ws);                       // 64 KB
  float*  part   = (float*)(ws + (64u << 10));         // 512 KB
  ushort* Wh     = (ushort*)(ws + (576u << 10));       // 256 KB
  float*  biasf  = (float*)(ws + (832u << 10));        // 2.5 KB
  ushort* xT     = (ushort*)(ws + (1u << 20));         // 8 MB [1,9)
  ushort* attP0  = xT;                                 // aliases xT (dead after proj)
  ushort* thetaT = (ushort*)(ws + (9u << 20));         // 4 MB
  ushort* phiT   = (ushort*)(ws + (13u << 20));        // 4 MB
  ushort* gbuf   = (ushort*)(ws + (17u << 20));        // 4 MB, end 21 MB
  ushort* attP1  = (ushort*)(ws + (21u << 20));        // 8 MB (ws >= 30 MB: proven R6)

  k_trc<<<1539, 256, 0, stream>>>(x, xT, tw, pw, gw, ww, tb, pb, gb, wb, Wh, biasf);
  k_proj<<<dim3(128, 4), 256, 0, stream>>>(xT, Wh, biasf, thetaT, phiT, gbuf);
  k_stats<<<dim3(16, 8, 4), 256, 0, stream>>>(phiT, thetaT, part);
  k_lse<<<64, 256, 0, stream>>>(part, o2);
  k_attn<<<dim3(64, 2, 4), 256, 0, stream>>>(phiT, thetaT, gbuf, o2, attP0, attP1);
  k_out<<<dim3(128, 4), 256, 0, stream>>>(attP0, attP1, Wh + 3 * 32768, biasf, x, d_out);
}

// Round 8
// 257.057 us; speedup vs baseline: 1.0111x; 1.0111x over previous
//
#include <hip/hip_runtime.h>
#include <hip/hip_bf16.h>

#define B_ 4
#define C_ 256
#define CI_ 128
#define P_ 4096
#define LOG2E 1.44269504088896340736f

typedef __attribute__((ext_vector_type(8))) _Float16 half8;
typedef __attribute__((ext_vector_type(2))) __fp16 fp16x2;
typedef __attribute__((ext_vector_type(8))) short short8;
typedef __attribute__((ext_vector_type(4))) short short4v;
typedef __attribute__((ext_vector_type(4))) float floatx4;

__device__ __forceinline__ float bf2f(ushort h) {
  union { unsigned u; float f; } v; v.u = ((unsigned)h) << 16; return v.f;
}
__device__ __forceinline__ ushort f2bf(float f) {
  union { float f; unsigned u; } v; v.f = f;
  unsigned r = v.u + 0x7FFFu + ((v.u >> 16) & 1u);
  return (ushort)(r >> 16);
}
__device__ __forceinline__ ushort f2h(float f) {
  _Float16 h = (_Float16)f;
  union { _Float16 h; ushort u; } v; v.h = h; return v.u;
}
__device__ __forceinline__ uint pk2h(float a, float b) {
  union { fp16x2 h2; uint u; } cv;
  cv.h2 = __builtin_amdgcn_cvt_pkrtz(a, b);
  return cv.u;
}
// Load 8 contiguous elements (bf16 or fp32 source) -> f16 frag.
__device__ __forceinline__ half8 ld8h(const void* src, size_t off, int is_bf16) {
  union { uint u[4]; half8 v; } r;
  if (is_bf16) {
    short8 x = *(const short8*)((const ushort*)src + off);
#pragma unroll
    for (int i = 0; i < 4; ++i)
      r.u[i] = pk2h(bf2f((ushort)x[2 * i]), bf2f((ushort)x[2 * i + 1]));
  } else {
    const float* f = (const float*)src + off;
    float4 a = *(const float4*)f, b = *(const float4*)(f + 4);
    r.u[0] = pk2h(a.x, a.y); r.u[1] = pk2h(a.z, a.w);
    r.u[2] = pk2h(b.x, b.y); r.u[3] = pk2h(b.z, b.w);
  }
  return r.v;
}
__device__ __forceinline__ float ldf(const void* src, int idx, int is_bf16) {
  return is_bf16 ? bf2f(((const ushort*)src)[idx]) : ((const float*)src)[idx];
}

#define MFMA16(a, b, c) __builtin_amdgcn_mfma_f32_16x16x32_f16((a), (b), (c), 0, 0, 0)

// Per-block dtype probe (deterministic). bf16 N(0,1) even-ushort exponents in
// [0x70,0x84] ~100%; fp32 low-mantissa halves ~8%. Call from all 256 threads.
__device__ __forceinline__ int detect_bf16(const ushort* __restrict__ xu) {
  __shared__ int cnt_;
  if (threadIdx.x == 0) cnt_ = 0;
  __syncthreads();
  int local = 0;
  int t = threadIdx.x & 255;
#pragma unroll
  for (int s = 0; s < 8; ++s) {
    ushort u = xu[(t * 8 + s) * 2];
    int e = (u >> 7) & 0xFF;
    local += (e >= 0x70 && e <= 0x84) ? 1 : 0;
  }
  atomicAdd(&cnt_, local);
  __syncthreads();
  return cnt_ > 1024;
}

// Fused transpose + projections. Per block: stage x[b][:, p0..p0+32] into LDS
// as f16 [p][c], then 3 GEMMs with W frags converted inline from source dtype.
// Outputs: thetaT/phiT (B,P,CI) f16 p-major; g (B,CI,P) f16.
__global__ __launch_bounds__(256, 4) void k_proj(
    const void* __restrict__ xv,
    const void* __restrict__ twv, const void* __restrict__ pwv,
    const void* __restrict__ gwv,
    const void* __restrict__ tbv, const void* __restrict__ pbv,
    const void* __restrict__ gbv,
    ushort* __restrict__ thetaT, ushort* __restrict__ phiT,
    ushort* __restrict__ g) {
  int is_bf16 = detect_bf16((const ushort*)xv);
  __shared__ __align__(16) ushort xtl[32][264];
  int t = threadIdx.x;
  int w = t >> 6, lane = t & 63, l = lane & 15, q = lane >> 4;
  int p0 = blockIdx.x * 32, b = blockIdx.y;
  // Phase A: transpose 256c x 32p tile into LDS (f16)
  {
    int c_loc = t >> 2;        // 0..63
    int p_loc = (t & 3) * 8;   // 0,8,16,24
#pragma unroll
    for (int cb = 0; cb < 4; ++cb) {
      size_t base = ((size_t)(b * C_) + cb * 64 + c_loc) * P_ + p0 + p_loc;
      float vv[8];
      if (is_bf16) {
        short8 v = *(const short8*)((const ushort*)xv + base);
#pragma unroll
        for (int i = 0; i < 8; ++i) vv[i] = bf2f((ushort)v[i]);
      } else {
        const float* xf = (const float*)xv;
        float4 v0 = *(const float4*)(xf + base);
        float4 v1 = *(const float4*)(xf + base + 4);
        vv[0] = v0.x; vv[1] = v0.y; vv[2] = v0.z; vv[3] = v0.w;
        vv[4] = v1.x; vv[5] = v1.y; vv[6] = v1.z; vv[7] = v1.w;
      }
#pragma unroll
      for (int i = 0; i < 8; ++i) {
        int iw = (i + t) & 7;  // bank rotation
        xtl[p_loc + iw][cb * 64 + c_loc] = f2h(vv[iw]);
      }
    }
  }
  __syncthreads();
  // Phase B: wave w handles k-rows w*96 .. w*96+96 (6 tiles of 16)
  const void* wsrc[3] = {twv, pwv, gwv};
  const void* bsrc[3] = {tbv, pbv, gbv};
  floatx4 acc[2][6];
#pragma unroll
  for (int ps = 0; ps < 2; ++ps)
#pragma unroll
    for (int ks = 0; ks < 6; ++ks) acc[ps][ks] = (floatx4){0.f, 0.f, 0.f, 0.f};
  int prj[6], kloc[6];
#pragma unroll
  for (int ks = 0; ks < 6; ++ks) {
    int kg = w * 96 + ks * 16;
    prj[ks] = kg >> 7;
    kloc[ks] = kg & 127;
  }
  for (int c = 0; c < C_; c += 32) {
    half8 av[2], wv[6];
#pragma unroll
    for (int ps = 0; ps < 2; ++ps)
      av[ps] = *(const half8*)&xtl[ps * 16 + l][c + q * 8];
#pragma unroll
    for (int ks = 0; ks < 6; ++ks)
      wv[ks] = ld8h(wsrc[prj[ks]], (size_t)(kloc[ks] + l) * C_ + c + q * 8, is_bf16);
#pragma unroll
    for (int ps = 0; ps < 2; ++ps)
#pragma unroll
      for (int ks = 0; ks < 6; ++ks)
        acc[ps][ks] = MFMA16(av[ps], wv[ks], acc[ps][ks]);
  }
#pragma unroll
  for (int ks = 0; ks < 6; ++ks) {
    float bias = ldf(bsrc[prj[ks]], kloc[ks] + l, is_bf16);
#pragma unroll
    for (int ps = 0; ps < 2; ++ps) {
      floatx4 d = acc[ps][ks];
      if (prj[ks] < 2) {
        ushort* dst = (prj[ks] == 0 ? thetaT : phiT) +
                      ((size_t)(b * P_) + p0 + ps * 16 + q * 4) * CI_ + kloc[ks] + l;
#pragma unroll
        for (int r = 0; r < 4; ++r) dst[(size_t)r * CI_] = f2h(d[r] + bias);
      } else {
        ushort* dst = g + ((size_t)(b * CI_) + kloc[ks] + l) * P_ + p0 + ps * 16 + q * 4;
        short4v pk;
#pragma unroll
        for (int r = 0; r < 4; ++r) pk[r] = (short)f2h(d[r] + bias);
        *(short4v*)dst = pk;
      }
    }
  }
}

// Pass A: partial sums of exp2(S*log2e - 64) over j-splits.
// grid (P/256, 8, B), 256 threads; wave w covers i rows [w*64, w*64+64).
__global__ __launch_bounds__(256, 2) void k_stats(
    const ushort* __restrict__ phiT, const ushort* __restrict__ thetaT,
    float* __restrict__ part) {
  int t = threadIdx.x, w = t >> 6, lane = t & 63, l = lane & 15, q = lane >> 4;
  int i0 = blockIdx.x * 256, j0 = blockIdx.y * 512, b = blockIdx.z;
  half8 av[4][4];
#pragma unroll
  for (int is = 0; is < 4; ++is) {
    const ushort* pr = phiT + ((size_t)(b * P_) + i0 + w * 64 + is * 16 + l) * CI_;
#pragma unroll
    for (int ks = 0; ks < 4; ++ks) av[is][ks] = *(const half8*)(pr + ks * 32 + q * 8);
  }
  float sum[4][4];
#pragma unroll
  for (int is = 0; is < 4; ++is)
#pragma unroll
    for (int r = 0; r < 4; ++r) sum[is][r] = 0.f;
  const ushort* tb0 = thetaT + (size_t)b * P_ * CI_;
  for (int jc = 0; jc < 16; ++jc) {
    int j = j0 + jc * 32;
    half8 bv[2][4];
#pragma unroll
    for (int js = 0; js < 2; ++js) {
      const ushort* tr = tb0 + (size_t)(j + js * 16 + l) * CI_;
#pragma unroll
      for (int ks = 0; ks < 4; ++ks) bv[js][ks] = *(const half8*)(tr + ks * 32 + q * 8);
    }
    floatx4 accS[4][2];
#pragma unroll
    for (int is = 0; is < 4; ++is)
#pragma unroll
      for (int js = 0; js < 2; ++js) accS[is][js] = (floatx4){0.f, 0.f, 0.f, 0.f};
#pragma unroll
    for (int ks = 0; ks < 4; ++ks)
#pragma unroll
      for (int is = 0; is < 4; ++is)
#pragma unroll
        for (int js = 0; js < 2; ++js)
          accS[is][js] = MFMA16(av[is][ks], bv[js][ks], accS[is][js]);
#pragma unroll
    for (int is = 0; is < 4; ++is)
#pragma unroll
      for (int js = 0; js < 2; ++js)
#pragma unroll
        for (int r = 0; r < 4; ++r)
          sum[is][r] += exp2f(fmaf(accS[is][js][r], LOG2E, -64.f));
  }
#pragma unroll
  for (int d = 1; d < 16; d <<= 1)
#pragma unroll
    for (int is = 0; is < 4; ++is)
#pragma unroll
      for (int r = 0; r < 4; ++r) sum[is][r] += __shfl_xor(sum[is][r], d, 64);
  if (l == 0) {
#pragma unroll
    for (int is = 0; is < 4; ++is)
#pragma unroll
      for (int r = 0; r < 4; ++r)
        part[((size_t)blockIdx.y * B_ + b) * P_ + i0 + w * 64 + is * 16 + q * 4 + r] =
            sum[is][r];
  }
}

// Pass B (R6 structure + inline lse): j-tile 128 x i-half per block.
// grid (32, 2, B), 256 threads. lse for this i-half computed into LDS first.
__global__ __launch_bounds__(256, 2) void k_attn(
    const ushort* __restrict__ phiT, const ushort* __restrict__ thetaT,
    const ushort* __restrict__ g, const float* __restrict__ part,
    ushort* __restrict__ attP0, ushort* __restrict__ attP1) {
  __shared__ __align__(16) ushort thL[128][136];
  __shared__ __align__(16) ushort eL[128][136];
  __shared__ __align__(16) float oL[2048];
  int t = threadIdx.x;
  int w = t >> 6, lane = t & 63, l = lane & 15, q = lane >> 4;
  int j0 = blockIdx.x * 128, ih = blockIdx.y, b = blockIdx.z;
  int istart = ih * 2048;
  // stage theta j-tile (128 x 128 f16)
#pragma unroll
  for (int it = 0; it < 8; ++it) {
    int lin = it * 256 + t, row = lin >> 4, cg = (lin & 15) * 8;
    *(short8*)&thL[row][cg] =
        *(const short8*)(thetaT + ((size_t)(b * P_) + j0 + row) * CI_ + cg);
  }
  // lse for this i-half: oL[iloc] = log2(sum_js part) + 64
#pragma unroll
  for (int z = 0; z < 8; ++z) {
    int iloc = z * 256 + t;
    float s = 0.f;
#pragma unroll
    for (int js = 0; js < 8; ++js)
      s += part[((size_t)js * B_ + b) * P_ + istart + iloc];
    oL[iloc] = log2f(s) + 64.f;
  }
  floatx4 accA[2][8];
#pragma unroll
  for (int cs = 0; cs < 2; ++cs)
#pragma unroll
    for (int js = 0; js < 8; ++js) accA[cs][js] = (floatx4){0.f, 0.f, 0.f, 0.f};
  __syncthreads();
  half8 af[2][4];
  float4 ov[2];
#pragma unroll
  for (int is = 0; is < 2; ++is) {
    int iG = istart + w * 32 + is * 16;
    const ushort* pr = phiT + ((size_t)(b * P_) + iG + l) * CI_;
#pragma unroll
    for (int ks = 0; ks < 4; ++ks) af[is][ks] = *(const half8*)(pr + ks * 32 + q * 8);
    ov[is] = *(const float4*)&oL[w * 32 + is * 16 + q * 4];
  }
  for (int ic = 0; ic < 16; ++ic) {
    int ibase = istart + ic * 128;
    // g loads issued early; consumed in phase 2
    half8 gf[2][4];
#pragma unroll
    for (int cs = 0; cs < 2; ++cs) {
      const ushort* gr = g + ((size_t)(b * CI_) + w * 32 + cs * 16 + l) * P_ + ibase;
#pragma unroll
      for (int ks = 0; ks < 4; ++ks) gf[cs][ks] = *(const half8*)(gr + ks * 32 + q * 8);
    }
    // phase 1: S = phi . theta^T
    floatx4 accS[2][8];
#pragma unroll
    for (int is = 0; is < 2; ++is)
#pragma unroll
      for (int js = 0; js < 8; ++js) accS[is][js] = (floatx4){0.f, 0.f, 0.f, 0.f};
#pragma unroll
    for (int ks = 0; ks < 4; ++ks) {
      half8 bf[8];
#pragma unroll
      for (int js = 0; js < 8; ++js) bf[js] = *(const half8*)&thL[js * 16 + l][ks * 32 + q * 8];
#pragma unroll
      for (int is = 0; is < 2; ++is)
#pragma unroll
        for (int js = 0; js < 8; ++js) accS[is][js] = MFMA16(af[is][ks], bf[js], accS[is][js]);
    }
    // E = exp2(S*log2e - o2) <= 1; pack pairwise
    uint2 ep[2][8];
#pragma unroll
    for (int is = 0; is < 2; ++is)
#pragma unroll
      for (int js = 0; js < 8; ++js) {
        float e0 = exp2f(fminf(fmaf(accS[is][js][0], LOG2E, -ov[is].x), 0.5f));
        float e1 = exp2f(fminf(fmaf(accS[is][js][1], LOG2E, -ov[is].y), 0.5f));
        float e2 = exp2f(fminf(fmaf(accS[is][js][2], LOG2E, -ov[is].z), 0.5f));
        float e3 = exp2f(fminf(fmaf(accS[is][js][3], LOG2E, -ov[is].w), 0.5f));
        ep[is][js] = (uint2){pk2h(e0, e1), pk2h(e2, e3)};
      }
    __syncthreads();  // prev phase 2 done reading eL
#pragma unroll
    for (int is = 0; is < 2; ++is)
#pragma unroll
      for (int js = 0; js < 8; ++js)
        *(uint2*)&eL[js * 16 + l][w * 32 + is * 16 + q * 4] = ep[is][js];
    __syncthreads();  // E ready
    // prefetch next chunk's phi frags + o2 (covered by phase 2)
    if (ic < 15) {
      int nb = istart + (ic + 1) * 128;
#pragma unroll
      for (int is = 0; is < 2; ++is) {
        int iG = nb + w * 32 + is * 16;
        const ushort* pr = phiT + ((size_t)(b * P_) + iG + l) * CI_;
#pragma unroll
        for (int ks = 0; ks < 4; ++ks) af[is][ks] = *(const half8*)(pr + ks * 32 + q * 8);
        ov[is] = *(const float4*)&oL[(nb - istart) + w * 32 + is * 16 + q * 4];
      }
    }
    // phase 2: attA += g . E
#pragma unroll
    for (int ks = 0; ks < 4; ++ks) {
      half8 ef[8];
#pragma unroll
      for (int js = 0; js < 8; ++js) ef[js] = *(const half8*)&eL[js * 16 + l][ks * 32 + q * 8];
#pragma unroll
      for (int cs = 0; cs < 2; ++cs)
#pragma unroll
        for (int js = 0; js < 8; ++js) accA[cs][js] = MFMA16(gf[cs][ks], ef[js], accA[cs][js]);
    }
  }
  ushort* ap = (ih == 0 ? attP0 : attP1);
#pragma unroll
  for (int cs = 0; cs < 2; ++cs)
#pragma unroll
    for (int js = 0; js < 8; ++js) {
      uint2 pk = (uint2){pk2h(accA[cs][js][0], accA[cs][js][1]),
                         pk2h(accA[cs][js][2], accA[cs][js][3])};
      *(uint2*)(ap + ((size_t)(b * P_) + j0 + js * 16 + l) * CI_ +
                w * 32 + cs * 16 + q * 4) = pk;
    }
}

// Final: attsum = attP0+attP1 (f16, [p][c]); out = Ww*attsum + wb + x.
// Ww/wb converted inline from source dtype.
__global__ __launch_bounds__(256, 4) void k_out(
    const ushort* __restrict__ attP0, const ushort* __restrict__ attP1,
    const void* __restrict__ wwv, const void* __restrict__ wbv,
    const void* __restrict__ xv, void* __restrict__ outv) {
  int is_bf16 = detect_bf16((const ushort*)xv);
  int t = threadIdx.x;
  int w = t >> 6, lane = t & 63, l = lane & 15, q = lane >> 4;
  int p0 = blockIdx.x * 32, b = blockIdx.y;
  floatx4 accR[4][2];
#pragma unroll
  for (int kk = 0; kk < 4; ++kk)
#pragma unroll
    for (int js = 0; js < 2; ++js) accR[kk][js] = (floatx4){0.f, 0.f, 0.f, 0.f};
#pragma unroll
  for (int ks = 0; ks < 4; ++ks) {
    half8 wf[4], af[2];
#pragma unroll
    for (int kk = 0; kk < 4; ++kk)
      wf[kk] = ld8h(wwv, (size_t)(w * 64 + kk * 16 + l) * CI_ + ks * 32 + q * 8, is_bf16);
#pragma unroll
    for (int js = 0; js < 2; ++js) {
      size_t off = ((size_t)(b * P_) + p0 + js * 16 + l) * CI_ + ks * 32 + q * 8;
      half8 s = *(const half8*)(attP0 + off);
      s = s + *(const half8*)(attP1 + off);
      af[js] = s;
    }
#pragma unroll
    for (int kk = 0; kk < 4; ++kk)
#pragma unroll
      for (int js = 0; js < 2; ++js) accR[kk][js] = MFMA16(wf[kk], af[js], accR[kk][js]);
  }
#pragma unroll
  for (int kk = 0; kk < 4; ++kk)
#pragma unroll
    for (int r = 0; r < 4; ++r) {
      int c = w * 64 + kk * 16 + q * 4 + r;
      float bias = ldf(wbv, c, is_bf16);
#pragma unroll
      for (int js = 0; js < 2; ++js) {
        int p = p0 + js * 16 + l;
        size_t idx = ((size_t)(b * C_) + c) * P_ + p;
        float val = accR[kk][js][r] + bias;
        if (is_bf16) {
          ((ushort*)outv)[idx] = f2bf(bf2f(((const ushort*)xv)[idx]) + val);
        } else {
          ((float*)outv)[idx] = ((const float*)xv)[idx] + val;
        }
      }
    }
}

extern "C" void kernel_launch(void* const* d_in, const int* in_sizes, int n_in,
                              void* d_out, int out_size, void* d_ws, size_t ws_size,
                              hipStream_t stream) {
  const void* x  = d_in[0];
  const void* tw = d_in[1];
  const void* tb = d_in[2];
  const void* pw = d_in[3];
  const void* pb = d_in[4];
  const void* gw = d_in[5];
  const void* gb = d_in[6];
  const void* ww = d_in[7];
  const void* wb = d_in[8];
  char* ws = (char*)d_ws;
  float*  part   = (float*)(ws);                 // 512 KB
  ushort* attP0  = (ushort*)(ws + (1u << 20));   // 8 MB
  ushort* thetaT = (ushort*)(ws + (9u << 20));   // 4 MB
  ushort* phiT   = (ushort*)(ws + (13u << 20));  // 4 MB
  ushort* gbuf   = (ushort*)(ws + (17u << 20));  // 4 MB
  ushort* attP1  = (ushort*)(ws + (21u << 20));  // 8 MB (ws >= 30 MB: proven R6)

  k_proj<<<dim3(128, 4), 256, 0, stream>>>(x, tw, pw, gw, tb, pb, gb,
                                           thetaT, phiT, gbuf);
  k_stats<<<dim3(16, 8, 4), 256, 0, stream>>>(phiT, thetaT, part);
  k_attn<<<dim3(32, 2, 4), 256, 0, stream>>>(phiT, thetaT, gbuf, part, attP0, attP1);
  k_out<<<dim3(128, 4), 256, 0, stream>>>(attP0, attP1, ww, wb, x, d_out);
}